// Round 5
// baseline (241.005 us; speedup 1.0000x reference)
//
#include <hip/hip_runtime.h>
#include <hip/hip_bf16.h>

#define NROWS 131072
#define KEXP 16
#define MPC 128
#define DIMD 64

typedef float f32x4  __attribute__((ext_vector_type(4)));
typedef float f32x16 __attribute__((ext_vector_type(16)));
typedef short s16x8  __attribute__((ext_vector_type(8)));

#define L2E 1.4426950408889634f
#define LN2 0.6931471805599453f

static __device__ inline unsigned int b2u(__hip_bfloat162 h) {
    union { __hip_bfloat162 h; unsigned int u; } c;
    c.h = h;
    return c.u;
}

static __device__ inline int4 cvt8s(float4 f0, float4 f1, float sc) {
    __hip_bfloat162 p0 = __float22bfloat162_rn(make_float2(f0.x * sc, f0.y * sc));
    __hip_bfloat162 p1 = __float22bfloat162_rn(make_float2(f0.z * sc, f0.w * sc));
    __hip_bfloat162 p2 = __float22bfloat162_rn(make_float2(f1.x * sc, f1.y * sc));
    __hip_bfloat162 p3 = __float22bfloat162_rn(make_float2(f1.z * sc, f1.w * sc));
    int4 pk;
    pk.x = (int)b2u(p0); pk.y = (int)b2u(p1); pk.z = (int)b2u(p2); pk.w = (int)b2u(p3);
    return pk;
}

// async 16B/lane global->LDS DMA (wave-uniform LDS base + lane*16)
static __device__ inline void async_copy16(const void* g, void* l) {
    __builtin_amdgcn_global_load_lds(
        (const __attribute__((address_space(1))) unsigned int*)g,
        (__attribute__((address_space(3))) unsigned int*)l, 16, 0, 0);
}

// abff: per expert 20 chunks [mt(4)][c(5)] of 64 int4 (1 KB each) = 20 KB.
//   c<4 : A-frag, value j = a[k][mt*32 + (ul&31)][c*16 + (ul>>5)*8 + j] * L2E
//   c==4: bias chunk — A[m][k'=0] = b[k][mt*32+m] * L2E (ul<32, element 0), else 0
// Also zeroes out[] (replaces the hipMemsetAsync launch).
__global__ void prep_kernel(const float* __restrict__ a, const float* __restrict__ b,
                            short* __restrict__ abff, float* __restrict__ out) {
    const int u   = blockIdx.x * 256 + threadIdx.x;   // 0..20479
    const int k   = u / 1280;
    const int rem = u - k * 1280;
    const int mt  = rem / 320;
    const int rc  = rem - mt * 320;
    const int c   = rc >> 6;
    const int ul  = rc & 63;
    int4 pk;
    if (c < 4) {
        const float* p = a + (size_t)(k * MPC + mt * 32 + (ul & 31)) * DIMD
                           + c * 16 + (ul >> 5) * 8;
        pk = cvt8s(*(const float4*)(p), *(const float4*)(p + 4), L2E);
    } else {
        pk.x = 0; pk.y = 0; pk.z = 0; pk.w = 0;
        if (ul < 32) {
            union { __hip_bfloat16 h; unsigned short us; } cv;
            cv.h = __float2bfloat16(b[k * MPC + mt * 32 + ul] * L2E);
            pk.x = (int)cv.us;   // element 0 = bias, elements 1..7 = 0
        }
    }
    *(int4*)(abff + (size_t)u * 8) = pk;

    // zero the output (20480 threads grid-stride over 131072 floats)
    for (int i = u; i < NROWS; i += 80 * 256) out[i] = 0.f;
}

// Round-5 experiment: SAME structure as round 4 (verified correct, 55 us),
// ONE variable changed: true 8 blocks/CU occupancy.
//   - Round-4 counters showed occupancy stuck at 34% despite 20 KB LDS:
//     rocprof VGPR_Count=52 is ARCH regs only; +16 acc (f32x16) = 68 > 64
//     unified total -> still 4 waves/SIMD. __launch_bounds__(256,8) forces
//     total <= 64 (round 3 proved the bound itself reaches 72% occupancy;
//     its spills came from the fully-unrolled k-loop, which round 4 removed).
//   - A-fragments loaded JIT (single live Af) to hand the allocator ~12 regs
//     of slack so the bound is met WITHOUT scratch spills.
// Spill canary: WRITE_SIZE must stay ~1 MB.
__global__ __launch_bounds__(256, 8)
void fused_kernel(const float* __restrict__ x, const float* __restrict__ s,
                  const short* __restrict__ abff, float* __restrict__ out) {
    __shared__ int4 abuf[2][640];   // 2 x 10 KB

    const int tid  = threadIdx.x;
    const int w    = tid >> 6;
    const int l    = tid & 63;
    const int ln   = l & 31;
    const int half = l >> 5;

    const int family = blockIdx.x & 1;
    const int r0w    = (blockIdx.x >> 1) * 128 + w * 32;

    // persistent x B-fragment: Bf[c] = x[r0w + ln][c*16 + half*8 ..+7]
    union { int4 i; s16x8 v; } Bf[4];
#pragma unroll
    for (int c = 0; c < 4; ++c) {
        const float* gp = x + (size_t)(r0w + ln) * DIMD + c * 16 + half * 8;
        float4 f0 = *(const float4*)(gp);
        float4 f1 = *(const float4*)(gp + 4);
        Bf[c].i = cvt8s(f0, f1, 1.0f);
    }

    // constant bias-B: B[n][k'=0] = 1.0 (k'=0 lives on half==0 lanes, element 0)
    union { int4 i; s16x8 v; } Bones;
    Bones.i.x = (half == 0) ? 0x3F80 : 0;   // bf16(1.0) in element 0
    Bones.i.y = 0; Bones.i.z = 0; Bones.i.w = 0;

    const int kf0 = family * 8;

    // DMA initial stage (expert kf0, mtiles 0-1) into abuf[0]:
    // 10 chunks, wave w takes ch = w + 4*i
    {
        const short* src = abff + (size_t)kf0 * 10240;
#pragma unroll
        for (int i = 0; i < 3; ++i) {
            const int ch = w + 4 * i;
            if (ch < 10)
                async_copy16(src + ch * 512 + l * 8, (char*)&abuf[0][0] + ch * 1024);
        }
    }
    __syncthreads();   // barrier drains DMA (vmcnt0 before s_barrier)

    float racc = 0.f;

    for (int k = 0; k < 8; ++k) {   // runtime loop: keep code + registers small
        const int kf  = kf0 + k;
        const float sk2 = s[kf] * LN2;
        float esum = 0.f;

        // ---------- half-stage 0: compute abuf[0], prefetch half 1 -> abuf[1]
        {
            const short* src = abff + (size_t)kf * 10240 + 5120;
#pragma unroll
            for (int i = 0; i < 3; ++i) {
                const int ch = w + 4 * i;
                if (ch < 10)
                    async_copy16(src + ch * 512 + l * 8, (char*)&abuf[1][0] + ch * 1024);
            }
        }
#pragma unroll
        for (int mtl = 0; mtl < 2; ++mtl) {
            const short* base = (const short*)&abuf[0][0] + mtl * 5 * 512 + l * 8;
            f32x16 acc = {};
#pragma unroll
            for (int c = 0; c < 4; ++c) {
                s16x8 Af = *(const s16x8*)(base + c * 512);   // JIT load, short live range
                acc = __builtin_amdgcn_mfma_f32_32x32x16_bf16(Af, Bf[c].v, acc, 0, 0, 0);
            }
            {
                s16x8 Af = *(const s16x8*)(base + 4 * 512);
                acc = __builtin_amdgcn_mfma_f32_32x32x16_bf16(Af, Bones.v, acc, 0, 0, 0);
            }
            float s0 = 0.f, s1 = 0.f, s2 = 0.f, s3 = 0.f;
#pragma unroll
            for (int r = 0; r < 4; ++r) {
                s0 += __builtin_amdgcn_exp2f(acc[4 * r + 0]);
                s1 += __builtin_amdgcn_exp2f(acc[4 * r + 1]);
                s2 += __builtin_amdgcn_exp2f(acc[4 * r + 2]);
                s3 += __builtin_amdgcn_exp2f(acc[4 * r + 3]);
            }
            esum += (s0 + s1) + (s2 + s3);
        }
        __syncthreads();   // abuf[0] free; abuf[1] drained

        // ---------- half-stage 1: compute abuf[1], prefetch next expert -> abuf[0]
        if (k < 7) {
            const short* src = abff + (size_t)(kf + 1) * 10240;
#pragma unroll
            for (int i = 0; i < 3; ++i) {
                const int ch = w + 4 * i;
                if (ch < 10)
                    async_copy16(src + ch * 512 + l * 8, (char*)&abuf[0][0] + ch * 1024);
            }
        }
#pragma unroll
        for (int mtl = 0; mtl < 2; ++mtl) {
            const short* base = (const short*)&abuf[1][0] + mtl * 5 * 512 + l * 8;
            f32x16 acc = {};
#pragma unroll
            for (int c = 0; c < 4; ++c) {
                s16x8 Af = *(const s16x8*)(base + c * 512);
                acc = __builtin_amdgcn_mfma_f32_32x32x16_bf16(Af, Bf[c].v, acc, 0, 0, 0);
            }
            {
                s16x8 Af = *(const s16x8*)(base + 4 * 512);
                acc = __builtin_amdgcn_mfma_f32_32x32x16_bf16(Af, Bones.v, acc, 0, 0, 0);
            }
            float s0 = 0.f, s1 = 0.f, s2 = 0.f, s3 = 0.f;
#pragma unroll
            for (int r = 0; r < 4; ++r) {
                s0 += __builtin_amdgcn_exp2f(acc[4 * r + 0]);
                s1 += __builtin_amdgcn_exp2f(acc[4 * r + 1]);
                s2 += __builtin_amdgcn_exp2f(acc[4 * r + 2]);
                s3 += __builtin_amdgcn_exp2f(acc[4 * r + 3]);
            }
            esum += (s0 + s1) + (s2 + s3);
        }

        // combine m-halves (lanes l and l^32), accumulate weighted lse
        float tot = esum + __shfl_xor(esum, 32);
        racc = fmaf(sk2, __log2f(tot), racc);

        __syncthreads();   // abuf[1] free; abuf[0] (next expert) drained
    }

    // one atomic per row per family (lane halves hold identical tot-sums)
    if (half == 0)
        atomicAdd(&out[r0w + ln], racc);
}

extern "C" void kernel_launch(void* const* d_in, const int* in_sizes, int n_in,
                              void* d_out, int out_size, void* d_ws, size_t ws_size,
                              hipStream_t stream) {
    const float* x = (const float*)d_in[0];
    const float* s = (const float*)d_in[1];
    const float* a = (const float*)d_in[2];
    const float* b = (const float*)d_in[3];
    float* out = (float*)d_out;

    short* abff = (short*)d_ws;   // 16 experts x 20 KB = 320 KB

    prep_kernel<<<80, 256, 0, stream>>>(a, b, abff, out);
    fused_kernel<<<NROWS / 64, 256, 0, stream>>>(x, s, abff, out);
}

// Round 6
// 121.421 us; speedup vs baseline: 1.9849x; 1.9849x over previous
//
#include <hip/hip_runtime.h>
#include <hip/hip_bf16.h>

#define NROWS 131072
#define KEXP 16
#define MPC 128
#define DIMD 64

typedef float f32x4  __attribute__((ext_vector_type(4)));
typedef float f32x16 __attribute__((ext_vector_type(16)));
typedef short s16x8  __attribute__((ext_vector_type(8)));

#define L2E 1.4426950408889634f
#define LN2 0.6931471805599453f

static __device__ inline unsigned int b2u(__hip_bfloat162 h) {
    union { __hip_bfloat162 h; unsigned int u; } c;
    c.h = h;
    return c.u;
}

static __device__ inline int4 cvt8s(float4 f0, float4 f1, float sc) {
    __hip_bfloat162 p0 = __float22bfloat162_rn(make_float2(f0.x * sc, f0.y * sc));
    __hip_bfloat162 p1 = __float22bfloat162_rn(make_float2(f0.z * sc, f0.w * sc));
    __hip_bfloat162 p2 = __float22bfloat162_rn(make_float2(f1.x * sc, f1.y * sc));
    __hip_bfloat162 p3 = __float22bfloat162_rn(make_float2(f1.z * sc, f1.w * sc));
    int4 pk;
    pk.x = (int)b2u(p0); pk.y = (int)b2u(p1); pk.z = (int)b2u(p2); pk.w = (int)b2u(p3);
    return pk;
}

// async 16B/lane global->LDS DMA (wave-uniform LDS base + lane*16)
static __device__ inline void async_copy16(const void* g, void* l) {
    __builtin_amdgcn_global_load_lds(
        (const __attribute__((address_space(1))) unsigned int*)g,
        (__attribute__((address_space(3))) unsigned int*)l, 16, 0, 0);
}

// abff: per expert 20 chunks [mt(4)][c(5)] of 64 int4 (1 KB each) = 20 KB.
//   c<4 : A-frag, value j = a[k][mt*32 + (ul&31)][c*16 + (ul>>5)*8 + j] * L2E
//   c==4: bias chunk — A[m][k'=0] = b[k][mt*32+m] * L2E (ul<32, element 0), else 0
// Also zeroes out[] (replaces the hipMemsetAsync launch).
__global__ void prep_kernel(const float* __restrict__ a, const float* __restrict__ b,
                            short* __restrict__ abff, float* __restrict__ out) {
    const int u   = blockIdx.x * 256 + threadIdx.x;   // 0..20479
    const int k   = u / 1280;
    const int rem = u - k * 1280;
    const int mt  = rem / 320;
    const int rc  = rem - mt * 320;
    const int c   = rc >> 6;
    const int ul  = rc & 63;
    int4 pk;
    if (c < 4) {
        const float* p = a + (size_t)(k * MPC + mt * 32 + (ul & 31)) * DIMD
                           + c * 16 + (ul >> 5) * 8;
        pk = cvt8s(*(const float4*)(p), *(const float4*)(p + 4), L2E);
    } else {
        pk.x = 0; pk.y = 0; pk.z = 0; pk.w = 0;
        if (ul < 32) {
            union { __hip_bfloat16 h; unsigned short us; } cv;
            cv.h = __float2bfloat16(b[k * MPC + mt * 32 + ul] * L2E);
            pk.x = (int)cv.us;   // element 0 = bias, elements 1..7 = 0
        }
    }
    *(int4*)(abff + (size_t)u * 8) = pk;

    // zero the output (20480 threads grid-stride over 131072 floats)
    for (int i = u; i < NROWS; i += 80 * 256) out[i] = 0.f;
}

// Round-6: round-4 structure (verified, 55 us) with ONE change: the two
// independent mtile chains per half-stage are explicitly interleaved with TWO
// live accumulators. Rationale: occupancy is pinned at 4 waves/SIMD (<=64-reg
// total is infeasible — rounds 3/5 both spilled catastrophically; <=128 is the
// binding step), so latency must be hidden by per-wave ILP instead. Round-4's
// codegen (52+16 regs) kept ONE live acc -> serial 40-cyc MFMA chains and
// serial 128-cyc exp blocks. Budget at 4 waves/SIMD is 128 regs: spend +16 on
// acc1 so MFMA chain 1 executes while exp-block 0 issues (separate pipes).
// NO forced min-waves (launch_bounds (256,4) honest); spill canary WRITE_SIZE.
__global__ __launch_bounds__(256, 4)
void fused_kernel(const float* __restrict__ x, const float* __restrict__ s,
                  const short* __restrict__ abff, float* __restrict__ out) {
    __shared__ int4 abuf[2][640];   // 2 x 10 KB

    const int tid  = threadIdx.x;
    const int w    = tid >> 6;
    const int l    = tid & 63;
    const int ln   = l & 31;
    const int half = l >> 5;

    const int family = blockIdx.x & 1;
    const int r0w    = (blockIdx.x >> 1) * 128 + w * 32;

    // persistent x B-fragment: Bf[c] = x[r0w + ln][c*16 + half*8 ..+7]
    union { int4 i; s16x8 v; } Bf[4];
#pragma unroll
    for (int c = 0; c < 4; ++c) {
        const float* gp = x + (size_t)(r0w + ln) * DIMD + c * 16 + half * 8;
        float4 f0 = *(const float4*)(gp);
        float4 f1 = *(const float4*)(gp + 4);
        Bf[c].i = cvt8s(f0, f1, 1.0f);
    }

    // constant bias-B: B[n][k'=0] = 1.0 (k'=0 lives on half==0 lanes, element 0)
    union { int4 i; s16x8 v; } Bones;
    Bones.i.x = (half == 0) ? 0x3F80 : 0;   // bf16(1.0) in element 0
    Bones.i.y = 0; Bones.i.z = 0; Bones.i.w = 0;

    const int kf0 = family * 8;

    // DMA initial stage (expert kf0, mtiles 0-1) into abuf[0]:
    // 10 chunks, wave w takes ch = w + 4*i
    {
        const short* src = abff + (size_t)kf0 * 10240;
#pragma unroll
        for (int i = 0; i < 3; ++i) {
            const int ch = w + 4 * i;
            if (ch < 10)
                async_copy16(src + ch * 512 + l * 8, (char*)&abuf[0][0] + ch * 1024);
        }
    }
    __syncthreads();   // barrier drains DMA (vmcnt0 before s_barrier)

    float racc = 0.f;

    for (int k = 0; k < 8; ++k) {   // runtime loop: keep code + registers small
        const int kf  = kf0 + k;
        const float sk2 = s[kf] * LN2;
        float esum = 0.f;

        // ---------- half-stage 0: compute abuf[0], prefetch half 1 -> abuf[1]
        {
            const short* src = abff + (size_t)kf * 10240 + 5120;
#pragma unroll
            for (int i = 0; i < 3; ++i) {
                const int ch = w + 4 * i;
                if (ch < 10)
                    async_copy16(src + ch * 512 + l * 8, (char*)&abuf[1][0] + ch * 1024);
            }
        }
        {
            const short* base0 = (const short*)&abuf[0][0] + l * 8;          // mtile 0
            const short* base1 = (const short*)&abuf[0][0] + 2560 + l * 8;   // mtile 1
            f32x16 acc0 = {}, acc1 = {};
#pragma unroll
            for (int c = 0; c < 4; ++c) {
                s16x8 Af0 = *(const s16x8*)(base0 + c * 512);
                acc0 = __builtin_amdgcn_mfma_f32_32x32x16_bf16(Af0, Bf[c].v, acc0, 0, 0, 0);
                s16x8 Af1 = *(const s16x8*)(base1 + c * 512);
                acc1 = __builtin_amdgcn_mfma_f32_32x32x16_bf16(Af1, Bf[c].v, acc1, 0, 0, 0);
            }
            {
                s16x8 Af0 = *(const s16x8*)(base0 + 4 * 512);
                acc0 = __builtin_amdgcn_mfma_f32_32x32x16_bf16(Af0, Bones.v, acc0, 0, 0, 0);
                s16x8 Af1 = *(const s16x8*)(base1 + 4 * 512);
                acc1 = __builtin_amdgcn_mfma_f32_32x32x16_bf16(Af1, Bones.v, acc1, 0, 0, 0);
            }
            // exp-block 0 issues while chain-1 MFMAs still execute (diff pipes)
            float s0 = 0.f, s1 = 0.f, s2 = 0.f, s3 = 0.f;
            float t0 = 0.f, t1 = 0.f, t2 = 0.f, t3 = 0.f;
#pragma unroll
            for (int r = 0; r < 4; ++r) {
                s0 += __builtin_amdgcn_exp2f(acc0[4 * r + 0]);
                s1 += __builtin_amdgcn_exp2f(acc0[4 * r + 1]);
                s2 += __builtin_amdgcn_exp2f(acc0[4 * r + 2]);
                s3 += __builtin_amdgcn_exp2f(acc0[4 * r + 3]);
            }
#pragma unroll
            for (int r = 0; r < 4; ++r) {
                t0 += __builtin_amdgcn_exp2f(acc1[4 * r + 0]);
                t1 += __builtin_amdgcn_exp2f(acc1[4 * r + 1]);
                t2 += __builtin_amdgcn_exp2f(acc1[4 * r + 2]);
                t3 += __builtin_amdgcn_exp2f(acc1[4 * r + 3]);
            }
            esum += ((s0 + s1) + (s2 + s3)) + ((t0 + t1) + (t2 + t3));
        }
        __syncthreads();   // abuf[0] free; abuf[1] drained

        // ---------- half-stage 1: compute abuf[1], prefetch next expert -> abuf[0]
        if (k < 7) {
            const short* src = abff + (size_t)(kf + 1) * 10240;
#pragma unroll
            for (int i = 0; i < 3; ++i) {
                const int ch = w + 4 * i;
                if (ch < 10)
                    async_copy16(src + ch * 512 + l * 8, (char*)&abuf[0][0] + ch * 1024);
            }
        }
        {
            const short* base0 = (const short*)&abuf[1][0] + l * 8;          // mtile 2
            const short* base1 = (const short*)&abuf[1][0] + 2560 + l * 8;   // mtile 3
            f32x16 acc0 = {}, acc1 = {};
#pragma unroll
            for (int c = 0; c < 4; ++c) {
                s16x8 Af0 = *(const s16x8*)(base0 + c * 512);
                acc0 = __builtin_amdgcn_mfma_f32_32x32x16_bf16(Af0, Bf[c].v, acc0, 0, 0, 0);
                s16x8 Af1 = *(const s16x8*)(base1 + c * 512);
                acc1 = __builtin_amdgcn_mfma_f32_32x32x16_bf16(Af1, Bf[c].v, acc1, 0, 0, 0);
            }
            {
                s16x8 Af0 = *(const s16x8*)(base0 + 4 * 512);
                acc0 = __builtin_amdgcn_mfma_f32_32x32x16_bf16(Af0, Bones.v, acc0, 0, 0, 0);
                s16x8 Af1 = *(const s16x8*)(base1 + 4 * 512);
                acc1 = __builtin_amdgcn_mfma_f32_32x32x16_bf16(Af1, Bones.v, acc1, 0, 0, 0);
            }
            float s0 = 0.f, s1 = 0.f, s2 = 0.f, s3 = 0.f;
            float t0 = 0.f, t1 = 0.f, t2 = 0.f, t3 = 0.f;
#pragma unroll
            for (int r = 0; r < 4; ++r) {
                s0 += __builtin_amdgcn_exp2f(acc0[4 * r + 0]);
                s1 += __builtin_amdgcn_exp2f(acc0[4 * r + 1]);
                s2 += __builtin_amdgcn_exp2f(acc0[4 * r + 2]);
                s3 += __builtin_amdgcn_exp2f(acc0[4 * r + 3]);
            }
#pragma unroll
            for (int r = 0; r < 4; ++r) {
                t0 += __builtin_amdgcn_exp2f(acc1[4 * r + 0]);
                t1 += __builtin_amdgcn_exp2f(acc1[4 * r + 1]);
                t2 += __builtin_amdgcn_exp2f(acc1[4 * r + 2]);
                t3 += __builtin_amdgcn_exp2f(acc1[4 * r + 3]);
            }
            esum += ((s0 + s1) + (s2 + s3)) + ((t0 + t1) + (t2 + t3));
        }

        // combine m-halves (lanes l and l^32), accumulate weighted lse
        float tot = esum + __shfl_xor(esum, 32);
        racc = fmaf(sk2, __log2f(tot), racc);

        __syncthreads();   // abuf[1] free; abuf[0] (next expert) drained
    }

    // one atomic per row per family (lane halves hold identical tot-sums)
    if (half == 0)
        atomicAdd(&out[r0w + ln], racc);
}

extern "C" void kernel_launch(void* const* d_in, const int* in_sizes, int n_in,
                              void* d_out, int out_size, void* d_ws, size_t ws_size,
                              hipStream_t stream) {
    const float* x = (const float*)d_in[0];
    const float* s = (const float*)d_in[1];
    const float* a = (const float*)d_in[2];
    const float* b = (const float*)d_in[3];
    float* out = (float*)d_out;

    short* abff = (short*)d_ws;   // 16 experts x 20 KB = 320 KB

    prep_kernel<<<80, 256, 0, stream>>>(a, b, abff, out);
    fused_kernel<<<NROWS / 64, 256, 0, stream>>>(x, s, abff, out);
}